// Round 6
// baseline (533.688 us; speedup 1.0000x reference)
//
#include <hip/hip_runtime.h>
#include <stdint.h>

typedef unsigned short ushort_t;
typedef __bf16 bf16x8 __attribute__((ext_vector_type(8)));
typedef float f32x4 __attribute__((ext_vector_type(4)));
typedef ushort_t us4 __attribute__((ext_vector_type(4)));

#define MFMA16(a, b, c) __builtin_amdgcn_mfma_f32_16x16x32_bf16((a), (b), (c), 0, 0, 0)

constexpr int Bn = 4, Sn = 2048, Dn = 1024, Hn = 16, HDn = 64;
constexpr float SCALE = 0.125f;   // 1/sqrt(64)
constexpr float NEG = -1e9f;
constexpr unsigned NBLK = 512;

__device__ __forceinline__ float bf2f(ushort_t u) {
  unsigned x = ((unsigned)u) << 16;
  return __builtin_bit_cast(float, x);
}
__device__ __forceinline__ ushort_t f2bf(float f) {
  unsigned x = __builtin_bit_cast(unsigned, f);
  x = x + 0x7FFFu + ((x >> 16) & 1u);   // RNE
  return (ushort_t)(x >> 16);
}
__device__ __forceinline__ uint4 ld8_f32_bf16(const float* __restrict__ p) {
  float4 a = *(const float4*)p;
  float4 b = *(const float4*)(p + 4);
  union { ushort_t u[8]; uint4 v; } r;
  r.u[0] = f2bf(a.x); r.u[1] = f2bf(a.y); r.u[2] = f2bf(a.z); r.u[3] = f2bf(a.w);
  r.u[4] = f2bf(b.x); r.u[5] = f2bf(b.y); r.u[6] = f2bf(b.z); r.u[7] = f2bf(b.w);
  return r.v;
}
// async global->LDS, 16B per lane; LDS dest = wave-uniform base + lane*16
__device__ __forceinline__ void gl2lds16(const void* g, void* l) {
  __builtin_amdgcn_global_load_lds(
      (__attribute__((address_space(1))) void*)g,
      (__attribute__((address_space(3))) void*)l, 16, 0, 0);
}

// Generation-based grid barrier, no cooperative API. All atomics are
// device-scope RMWs (serialize at the coherence point, visible across XCDs).
// __threadfence release/acquire gives L2 writeback/invalidate so plain
// stores (O, G, R) are visible across XCDs after the barrier.
__device__ __forceinline__ void gridbar(unsigned* cnt, unsigned* gen) {
  __threadfence();                          // release
  __syncthreads();
  if (threadIdx.x == 0) {
    unsigned g = atomicAdd(gen, 0u);        // device-scope read
    if (atomicAdd(cnt, 1u) == NBLK - 1) {
      atomicExch(cnt, 0u);                  // reset for next use (RMW @ IC)
      __threadfence();
      atomicAdd(gen, 1u);                   // open the gate
    } else {
      while (atomicAdd(gen, 0u) == g) __builtin_amdgcn_s_sleep(8);
    }
  }
  __syncthreads();
  __threadfence();                          // acquire
}

// One-shot conversion of all f32 inputs to bf16: 3 X (4096 blocks each) then
// 4 W (512 blocks each). Xd: 3x8388608 elems contiguous; Wd: 4x1048576.
__global__ __launch_bounds__(256)
void cvt_all(const float* __restrict__ xq, const float* __restrict__ xk,
             const float* __restrict__ xv, const float* __restrict__ wq,
             const float* __restrict__ wk, const float* __restrict__ wv,
             const float* __restrict__ wo, ushort_t* __restrict__ Xd,
             ushort_t* __restrict__ Wd) {
  const int bid = blockIdx.x;
  if (bid < 12288) {
    const int which = bid >> 12;
    const float* s = which == 0 ? xq : which == 1 ? xk : xv;
    size_t i = ((size_t)(bid & 4095) * 256 + threadIdx.x) * 8;
    *(uint4*)(Xd + (size_t)which * 8388608 + i) = ld8_f32_bf16(s + i);
  } else {
    const int wb = bid - 12288, which = wb >> 9;
    const float* s = which == 0 ? wq : which == 1 ? wk : which == 2 ? wv : wo;
    size_t i = ((size_t)(wb & 511) * 256 + threadIdx.x) * 8;
    *(uint4*)(Wd + (size_t)which * 1048576 + i) = ld8_f32_bf16(s + i);
  }
}

// Fused Q/K/V projections (r2-proven 65 us version). z = 0/1/2 selects
// X, W, bias, dst, epilogue. Grid (x=row, y=col): same-row blocks spaced 64
// -> same XCD. z=0: Q scatter [B,H,S,HD]. z=1,2: transposed [B,H,HD,S] b64.
__global__ __launch_bounds__(256, 4)
void gemm_qkv(const ushort_t* __restrict__ Xb, const ushort_t* __restrict__ Wb,
              const float* __restrict__ bq, const float* __restrict__ bk,
              const float* __restrict__ bv, ushort_t* __restrict__ Qd,
              ushort_t* __restrict__ Ktd, ushort_t* __restrict__ Vtd) {
  constexpr int K = 1024;
  __shared__ __align__(16) ushort_t As[128 * 64];
  __shared__ __align__(16) ushort_t Bs[128 * 64];

  const int z = blockIdx.z;
  const ushort_t* A  = Xb + (size_t)z * 8388608;
  const ushort_t* Wt = Wb + (size_t)z * 1048576;
  const float* bias = z == 0 ? bq : z == 1 ? bk : bv;
  ushort_t* Cp = z == 0 ? Qd : z == 1 ? Ktd : Vtd;

  const int tid = threadIdx.x;
  const int lane = tid & 63, w = tid >> 6;
  const int quad = lane >> 4, l16 = lane & 15;
  const int wm = w >> 1, wn = w & 1;
  const int row0 = blockIdx.x * 128;
  const int col0 = blockIdx.y * 128;

  const int sr = lane >> 3;
  const int sg = ((lane & 7) ^ (sr & 7)) * 8;
  const ushort_t* Ab = A  + (size_t)(row0 + w * 32 + sr) * K + sg;
  const ushort_t* Bb = Wt + (size_t)(col0 + w * 32 + sr) * K + sg;

  f32x4 acc[4][4] = {};

  for (int k0 = 0; k0 < K; k0 += 64) {
    __syncthreads();
#pragma unroll
    for (int i = 0; i < 4; ++i) {
      gl2lds16(Ab + (size_t)(i * 8) * K + k0, &As[(w * 32 + i * 8) * 64]);
      gl2lds16(Bb + (size_t)(i * 8) * K + k0, &Bs[(w * 32 + i * 8) * 64]);
    }
    __syncthreads();
#pragma unroll
    for (int ks = 0; ks < 2; ++ks) {
      const int kg = ((ks * 4 + quad) ^ (l16 & 7)) * 8;
      bf16x8 af[4], bfr[4];
#pragma unroll
      for (int mt = 0; mt < 4; ++mt)
        af[mt] = *(const bf16x8*)(&As[(wm * 64 + mt * 16 + l16) * 64 + kg]);
#pragma unroll
      for (int nt = 0; nt < 4; ++nt)
        bfr[nt] = *(const bf16x8*)(&Bs[(wn * 64 + nt * 16 + l16) * 64 + kg]);
#pragma unroll
      for (int mt = 0; mt < 4; ++mt)
#pragma unroll
        for (int nt = 0; nt < 4; ++nt)
          acc[mt][nt] = MFMA16(af[mt], bfr[nt], acc[mt][nt]);
    }
  }

#pragma unroll
  for (int mt = 0; mt < 4; ++mt) {
#pragma unroll
    for (int nt = 0; nt < 4; ++nt) {
      const int col = col0 + wn * 64 + nt * 16 + l16;
      const float bv4 = bias[col];
      const int rowb = row0 + wm * 64 + mt * 16 + quad * 4;
      if (z != 0) {          // transposed scatter: [b,h,hd,s], b64 over s
        const int b = rowb >> 11, s = rowb & (Sn - 1);
        const int h = col >> 6, hd = col & 63;
        us4 pk;
#pragma unroll
        for (int r = 0; r < 4; ++r) pk[r] = f2bf(acc[mt][nt][r] + bv4);
        *(us4*)(Cp + ((size_t)((b * Hn + h) * HDn + hd)) * Sn + s) = pk;
      } else {               // Q scatter: [b,h,s,hd]
#pragma unroll
        for (int r = 0; r < 4; ++r) {
          const int row = rowb + r;
          const int b = row >> 11, s = row & (Sn - 1);
          const int h = col >> 6, hd = col & 63;
          Cp[(((size_t)(b * Hn + h) * Sn + s) << 6) + hd] = f2bf(acc[mt][nt][r] + bv4);
        }
      }
    }
  }
}

// Fused tail: gtile -> gridbar -> scan_attn -> gridbar -> gemm_out.
// Grid 512 x 256thr, block beta = (bh = beta&63, tq = beta>>6).
// Residency: LDS 42KB -> 3 blocks/CU capacity; __launch_bounds__(256,2)
// guarantees >=2/CU -> all 512 resident, spin barrier is safe.
// No L2 flush between phases except the barrier's own fence -> phase-1 G
// stays in the (bh%8) XCD's L2 for phase 2 (same block, same XCD).
__global__ __launch_bounds__(256, 2)
void tail_fused(const ushort_t* __restrict__ Q, const ushort_t* __restrict__ Kt,
                const ushort_t* __restrict__ Vt, float* __restrict__ Gd,
                float* __restrict__ Rs, ushort_t* __restrict__ O,
                const ushort_t* __restrict__ Wo, const float* __restrict__ bo,
                float* __restrict__ Cout, unsigned* __restrict__ bar) {
  // [0,16384) Vts[2] / Kts+Vts / As   [16384,24576) Zs / tsum / Bs
  // [24576,32768) Ks / Bs             [32768,41984) Ss   [41984,43008) sfx
  __shared__ __align__(16) char smem[43008];

  const int tid = threadIdx.x, lane = tid & 63, w = tid >> 6;
  const int quad = lane >> 4, l16 = lane & 15;
  const int beta = blockIdx.x;
  const int bh = beta & 63, tq = beta >> 6;
  const int b = bh >> 4, h = bh & 15;
  const int sr = lane >> 3;
  const int sg = ((lane & 7) ^ (sr & 7)) * 8;
  const int q8 = lane & 7, h8 = lane >> 3;

  const ushort_t* Ktb = Kt + (size_t)bh * HDn * Sn;
  const ushort_t* Vtb = Vt + (size_t)bh * HDn * Sn;

  // ================= phase 1: gtile x4 (t = 4*tq .. 4*tq+3) =================
  {
    ushort_t* Kts = (ushort_t*)smem;
    ushort_t* VtsS = (ushort_t*)(smem + 8192);
    float* tsum = (float*)(smem + 16384);
#pragma unroll 1
    for (int j = 0; j < 4; ++j) {
      const int t = tq * 4 + j;
      __syncthreads();                  // LDS free from previous j
      if (tid < 64) tsum[tid] = 0.f;
#pragma unroll
      for (int c = 0; c < 2; ++c) {
        const int row = w * 16 + c * 8;
        gl2lds16(Ktb + (size_t)(row + sr) * Sn + t * 64 + sg, &Kts[row * 64]);
        gl2lds16(Vtb + (size_t)(row + sr) * Sn + t * 64 + sg, &VtsS[row * 64]);
      }
      __syncthreads();
      f32x4 zacc[4] = {};
#pragma unroll
      for (int ks = 0; ks < 2; ++ks) {
        const int kg = ((ks * 4 + quad) ^ (l16 & 7)) * 8;
        bf16x8 ak = *(const bf16x8*)(&Kts[(w * 16 + l16) * 64 + kg]);
#pragma unroll
        for (int nt = 0; nt < 4; ++nt) {
          bf16x8 bv8 = *(const bf16x8*)(&VtsS[(nt * 16 + l16) * 64 + kg]);
          zacc[nt] = MFMA16(ak, bv8, zacc[nt]);
        }
      }
      float* gd = Gd + (size_t)(bh * 32 + t) * 4096;
#pragma unroll
      for (int nt = 0; nt < 4; ++nt)
        *(f32x4*)(gd + (nt * 16 + l16) * 64 + w * 16 + quad * 4) = zacc[nt];
      {
        const int n = tid & 63, jj = tid >> 6;
        float p = 0.f;
#pragma unroll
        for (int gg2 = 0; gg2 < 2; ++gg2) {
          const int g2 = 2 * jj + gg2;
          union { uint4 v; ushort_t u[8]; } cc;
          cc.v = *(const uint4*)(&VtsS[n * 64 + ((g2 ^ (n & 7)) << 3)]);
#pragma unroll
          for (int e = 0; e < 8; ++e) p += bf2f(cc.u[e]);
        }
        atomicAdd(&tsum[n], p);
      }
      __syncthreads();
      if (tid < 64) Rs[(size_t)(bh * 32 + t) * 64 + tid] = tsum[tid];
    }
  }

  gridbar(bar, bar + 1);

  // ================= phase 2: scan_attn (g = tq) =================
  {
    ushort_t* Vts = (ushort_t*)smem;                       // [2][4096]
    ushort_t* Zs = (ushort_t*)(smem + 16384);
    ushort_t* Ks = (ushort_t*)(smem + 24576);
    ushort_t (*Ss)[72] = (ushort_t(*)[72])(smem + 32768);
    float (*sfx)[64] = (float(*)[64])(smem + 41984);

    const int g = tq;
    const int qt0 = g * 4;
    const ushort_t* Qb = Q + (size_t)bh * Sn * HDn;
    const float* Gb = Gd + (size_t)bh * 32 * 4096;
    const float* Rb = Rs + (size_t)bh * 32 * 64;

    // Z ownership: thread -> row n = tid>>2 (0..63), cols [zd0, zd0+16)
    const int zn = tid >> 2, zd0 = (tid & 3) * 16;
    const float* gthr = Gb + zn * 64 + zd0;

    uint4  kvr[2][2];
    bf16x8 bqr[2][2];
    f32x4  gq[2][4];

    // prologue: issue all tile-qt0 loads (fly under sfx + prefix stream)
    {
      const int q0 = qt0 * 64;
#pragma unroll
      for (int c = 0; c < 2; ++c) {
        const int row = w * 16 + c * 8;
        gl2lds16(Vtb + (size_t)(row + sr) * Sn + q0 + sg, &Vts[row * 64]);
        kvr[0][c] = *(const uint4*)(Ktb + (size_t)(w * 16 + c * 8 + h8) * Sn + q0 + q8 * 8);
      }
#pragma unroll
      for (int ks = 0; ks < 2; ++ks)
        bqr[0][ks] = *(const bf16x8*)(Qb + (size_t)(q0 + w * 16 + l16) * HDn + (ks * 4 + quad) * 8);
#pragma unroll
      for (int j = 0; j < 4; ++j)
        gq[0][j] = *(const f32x4*)(gthr + (size_t)qt0 * 4096 + 4 * j);
    }

    // local suffix-V: sfx[i][n] = sum_{tau > qt0+i} R[tau][n]
    if (tid < 64) {
      float acc = 0.f;
      for (int tau = 31; tau >= qt0; --tau) {
        if (tau < qt0 + 4) sfx[tau - qt0][tid] = acc;
        acc += Rb[(size_t)tau * 64 + tid];
      }
    }

    // register prefix: Zacc = sum_{tau < qt0} G_tau   (ascending, f32)
    f32x4 Zacc[4] = {};
#pragma unroll 4
    for (int tau = 0; tau < qt0; ++tau) {
#pragma unroll
      for (int j = 0; j < 4; ++j)
        Zacc[j] += *(const f32x4*)(gthr + (size_t)tau * 4096 + 4 * j);
    }

#pragma unroll 4
    for (int i = 0; i < 4; ++i) {
      const int cur = i & 1;
      const int qt = qt0 + i, q0 = qt * 64;

      __syncthreads();   // B1: compute i-1 done (Zs/Ks free); i=0: sfx cover

      // write Z for this q-tile from regs into swizzled LDS layout
#pragma unroll
      for (int j = 0; j < 4; ++j) {
        const int d = zd0 + 4 * j;
        us4 pk;
#pragma unroll
        for (int r = 0; r < 4; ++r) pk[r] = f2bf(SCALE * Zacc[j][r]);
        *(us4*)(&Zs[zn * 64 + (((d >> 3) ^ (zn & 7)) << 3) + (d & 7)]) = pk;
      }
      // transpose-write diagonal K tile (regs -> Ks, rotated+swizzled)
#pragma unroll
      for (int c = 0; c < 2; ++c) {
        const int hd = w * 16 + c * 8 + h8;
        const int G = hd >> 3;
        const ushort_t* ku = (const ushort_t*)&kvr[cur][c];
#pragma unroll
        for (int j = 0; j < 8; ++j) {
          const int e = (j + q8) & 7;
          const int s = q8 * 8 + e;
          Ks[s * 64 + ((G ^ e) << 3) + (hd & 7)] = ku[e];
        }
      }

      __syncthreads();   // B2: ds_writes visible + V(qt) staging drained

      if (i < 3) {       // issue next-tile loads; fly under compute(i)
        const int q1 = (qt + 1) * 64, nxt = 1 - cur;
#pragma unroll
        for (int c = 0; c < 2; ++c) {
          const int row = w * 16 + c * 8;
          gl2lds16(Vtb + (size_t)(row + sr) * Sn + q1 + sg, &Vts[nxt * 4096 + row * 64]);
          kvr[nxt][c] = *(const uint4*)(Ktb + (size_t)(w * 16 + c * 8 + h8) * Sn + q1 + q8 * 8);
        }
#pragma unroll
        for (int ks = 0; ks < 2; ++ks)
          bqr[nxt][ks] = *(const bf16x8*)(Qb + (size_t)(q1 + w * 16 + l16) * HDn + (ks * 4 + quad) * 8);
#pragma unroll
        for (int j = 0; j < 4; ++j)
          gq[nxt][j] = *(const f32x4*)(gthr + (size_t)(qt + 1) * 4096 + 4 * j);
      }

      // ---- compute q-tile qt ----
      f32x4 oacc[4] = {};
#pragma unroll
      for (int ks = 0; ks < 2; ++ks) {        // prefix: O^T += Z' · Q^T
        const int kg = ((ks * 4 + quad) ^ (l16 & 7)) * 8;
#pragma unroll
        for (int nt = 0; nt < 4; ++nt) {
          bf16x8 az = *(const bf16x8*)(&Zs[(nt * 16 + l16) * 64 + kg]);
          oacc[nt] = MFMA16(az, bqr[cur][ks], oacc[nt]);
        }
      }
      f32x4 sacc[4] = {};
#pragma unroll
      for (int ks = 0; ks < 2; ++ks) {        // diagonal: S^T = K_d · Q^T
        const int kg = ((ks * 4 + quad) ^ (l16 & 7)) * 8;
#pragma unroll
        for (int nt = 0; nt < 4; ++nt) {
          bf16x8 ak = *(const bf16x8*)(&Ks[(nt * 16 + l16) * 64 + kg]);
          sacc[nt] = MFMA16(ak, bqr[cur][ks], sacc[nt]);
        }
      }
      const int qrel = w * 16 + l16;          // mask + scale -> Ss (b64, intra-wave)
#pragma unroll
      for (int nt = 0; nt < 4; ++nt) {
        const int kb = nt * 16 + quad * 4;
        us4 pk;
#pragma unroll
        for (int r = 0; r < 4; ++r) {
          float val = (kb + r > qrel) ? NEG : sacc[nt][r] * SCALE;
          pk[r] = f2bf(val);
        }
        *(us4*)(&Ss[qrel][kb]) = pk;
      }
#pragma unroll
      for (int ks = 0; ks < 2; ++ks) {        // O^T += V_d^T · S_d^T
        bf16x8 bs = *(const bf16x8*)(&Ss[qrel][ks * 32 + quad * 8]);
#pragma unroll
        for (int nt = 0; nt < 4; ++nt) {
          bf16x8 av = *(const bf16x8*)(&Vts[cur * 4096 + (nt * 16 + l16) * 64 + (((ks * 4 + quad) ^ (l16 & 7)) << 3)]);
          oacc[nt] = MFMA16(av, bs, oacc[nt]);
        }
      }

      // masked tail + store O[b,s,d] (b64 over n)
      const int s = q0 + w * 16 + l16;
#pragma unroll
      for (int nt = 0; nt < 4; ++nt) {
        const int nb = nt * 16 + quad * 4;
        float4 s4 = *(const float4*)(&sfx[i][nb]);
        us4 pk;
        pk[0] = f2bf(oacc[nt][0] + NEG * s4.x);
        pk[1] = f2bf(oacc[nt][1] + NEG * s4.y);
        pk[2] = f2bf(oacc[nt][2] + NEG * s4.z);
        pk[3] = f2bf(oacc[nt][3] + NEG * s4.w);
        *(us4*)(&O[((size_t)(b * Sn + s)) * Dn + h * 64 + nb]) = pk;
      }

      // advance prefix: Zacc += G_qt (loads issued one iteration ago)
#pragma unroll
      for (int j = 0; j < 4; ++j) Zacc[j] += gq[cur][j];
    }
  }

  gridbar(bar, bar + 1);

  // ================= phase 3: gemm_out (row0 = bh*128, col0 = tq*128) ======
  {
    constexpr int K = 1024;
    ushort_t* As = (ushort_t*)smem;
    ushort_t* Bs = (ushort_t*)(smem + 16384);
    const int wm = w >> 1, wn = w & 1;
    const int row0 = bh * 128;
    const int col0 = tq * 128;
    const ushort_t* Ab = O  + (size_t)(row0 + w * 32 + sr) * K + sg;
    const ushort_t* Bb = Wo + (size_t)(col0 + w * 32 + sr) * K + sg;

    f32x4 acc[4][4] = {};

    for (int k0 = 0; k0 < K; k0 += 64) {
      __syncthreads();
#pragma unroll
      for (int i = 0; i < 4; ++i) {
        gl2lds16(Ab + (size_t)(i * 8) * K + k0, &As[(w * 32 + i * 8) * 64]);
        gl2lds16(Bb + (size_t)(i * 8) * K + k0, &Bs[(w * 32 + i * 8) * 64]);
      }
      __syncthreads();
#pragma unroll
      for (int ks = 0; ks < 2; ++ks) {
        const int kg = ((ks * 4 + quad) ^ (l16 & 7)) * 8;
        bf16x8 af[4], bfr[4];
#pragma unroll
        for (int mt = 0; mt < 4; ++mt)
          af[mt] = *(const bf16x8*)(&As[(wm * 64 + mt * 16 + l16) * 64 + kg]);
#pragma unroll
        for (int nt = 0; nt < 4; ++nt)
          bfr[nt] = *(const bf16x8*)(&Bs[(wn * 64 + nt * 16 + l16) * 64 + kg]);
#pragma unroll
        for (int mt = 0; mt < 4; ++mt)
#pragma unroll
          for (int nt = 0; nt < 4; ++nt)
            acc[mt][nt] = MFMA16(af[mt], bfr[nt], acc[mt][nt]);
      }
    }

#pragma unroll
    for (int mt = 0; mt < 4; ++mt)
#pragma unroll
      for (int nt = 0; nt < 4; ++nt) {
        const int col = col0 + wn * 64 + nt * 16 + l16;
        const float bv = bo[col];
        const int rowb = row0 + wm * 64 + mt * 16 + quad * 4;
#pragma unroll
        for (int r = 0; r < 4; ++r)
          Cout[(size_t)(rowb + r) * 1024 + col] = acc[mt][nt][r] + bv;
      }
  }
}

extern "C" void kernel_launch(void* const* d_in, const int* in_sizes, int n_in,
                              void* d_out, int out_size, void* d_ws, size_t ws_size,
                              hipStream_t stream) {
  const float* Xq = (const float*)d_in[0];
  const float* Xk = (const float*)d_in[1];
  const float* Xv = (const float*)d_in[2];
  // d_in[3]: causal mask (int32) — tril, handled analytically
  const float* Wq = (const float*)d_in[4];
  const float* bq = (const float*)d_in[5];
  const float* Wk = (const float*)d_in[6];
  const float* bk = (const float*)d_in[7];
  const float* Wv = (const float*)d_in[8];
  const float* bv = (const float*)d_in[9];
  const float* Wo = (const float*)d_in[10];
  const float* bo = (const float*)d_in[11];

  // ws (MiB): [0,48) Xb(3) | [48,56) Wb(4) | [56,72) Q | [72,88) Kt |
  // [88,104) Vt | [120,136) O | [144,176) G f32 | [176,176.5) R f32 |
  // [200, +64B) grid-barrier {cnt, gen}
  constexpr size_t MiB = 1024 * 1024;
  char* ws = (char*)d_ws;
  ushort_t* Xb  = (ushort_t*)(ws);
  ushort_t* Wb  = (ushort_t*)(ws + 48 * MiB);
  ushort_t* Qb  = (ushort_t*)(ws + 56 * MiB);
  ushort_t* Ktb = (ushort_t*)(ws + 72 * MiB);
  ushort_t* Vtb = (ushort_t*)(ws + 88 * MiB);
  ushort_t* Ob  = (ushort_t*)(ws + 120 * MiB);
  float*    Gd  = (float*)   (ws + 144 * MiB);
  float*    Rsum= (float*)   (ws + 176 * MiB);
  unsigned* bar = (unsigned*)(ws + 200 * MiB);

  hipMemsetAsync(bar, 0, 64, stream);   // cnt = gen = 0 each launch (captured)

  cvt_all<<<14336, 256, 0, stream>>>(Xq, Xk, Xv, Wq, Wk, Wv, Wo, Xb, Wb);
  gemm_qkv<<<dim3(64, 8, 3), 256, 0, stream>>>(Xb, Wb, bq, bk, bv, Qb, Ktb, Vtb);
  tail_fused<<<512, 256, 0, stream>>>(Qb, Ktb, Vtb, Gd, Rsum, Ob,
                                      Wb + (size_t)3 * 1048576, bo,
                                      (float*)d_out, bar);
}

// Round 7
// 290.668 us; speedup vs baseline: 1.8361x; 1.8361x over previous
//
#include <hip/hip_runtime.h>
#include <stdint.h>

typedef unsigned short ushort_t;
typedef __bf16 bf16x8 __attribute__((ext_vector_type(8)));
typedef float f32x4 __attribute__((ext_vector_type(4)));
typedef ushort_t us4 __attribute__((ext_vector_type(4)));

#define MFMA16(a, b, c) __builtin_amdgcn_mfma_f32_16x16x32_bf16((a), (b), (c), 0, 0, 0)

constexpr int Bn = 4, Sn = 2048, Dn = 1024, Hn = 16, HDn = 64;
constexpr float SCALE = 0.125f;   // 1/sqrt(64)
constexpr float NEG = -1e9f;

__device__ __forceinline__ float bf2f(ushort_t u) {
  unsigned x = ((unsigned)u) << 16;
  return __builtin_bit_cast(float, x);
}
__device__ __forceinline__ ushort_t f2bf(float f) {
  unsigned x = __builtin_bit_cast(unsigned, f);
  x = x + 0x7FFFu + ((x >> 16) & 1u);   // RNE
  return (ushort_t)(x >> 16);
}
__device__ __forceinline__ uint4 ld8_f32_bf16(const float* __restrict__ p) {
  float4 a = *(const float4*)p;
  float4 b = *(const float4*)(p + 4);
  union { ushort_t u[8]; uint4 v; } r;
  r.u[0] = f2bf(a.x); r.u[1] = f2bf(a.y); r.u[2] = f2bf(a.z); r.u[3] = f2bf(a.w);
  r.u[4] = f2bf(b.x); r.u[5] = f2bf(b.y); r.u[6] = f2bf(b.z); r.u[7] = f2bf(b.w);
  return r.v;
}
// async global->LDS, 16B per lane; LDS dest = wave-uniform base + lane*16
__device__ __forceinline__ void gl2lds16(const void* g, void* l) {
  __builtin_amdgcn_global_load_lds(
      (__attribute__((address_space(1))) void*)g,
      (__attribute__((address_space(3))) void*)l, 16, 0, 0);
}

// One-shot conversion of all f32 inputs to bf16: 3 X (4096 blocks each) then
// 4 W (512 blocks each). Xd: 3x8388608 elems contiguous; Wd: 4x1048576.
__global__ __launch_bounds__(256)
void cvt_all(const float* __restrict__ xq, const float* __restrict__ xk,
             const float* __restrict__ xv, const float* __restrict__ wq,
             const float* __restrict__ wk, const float* __restrict__ wv,
             const float* __restrict__ wo, ushort_t* __restrict__ Xd,
             ushort_t* __restrict__ Wd) {
  const int bid = blockIdx.x;
  if (bid < 12288) {
    const int which = bid >> 12;
    const float* s = which == 0 ? xq : which == 1 ? xk : xv;
    size_t i = ((size_t)(bid & 4095) * 256 + threadIdx.x) * 8;
    *(uint4*)(Xd + (size_t)which * 8388608 + i) = ld8_f32_bf16(s + i);
  } else {
    const int wb = bid - 12288, which = wb >> 9;
    const float* s = which == 0 ? wq : which == 1 ? wk : which == 2 ? wv : wo;
    size_t i = ((size_t)(wb & 511) * 256 + threadIdx.x) * 8;
    *(uint4*)(Wd + (size_t)which * 1048576 + i) = ld8_f32_bf16(s + i);
  }
}

// Fused Q/K/V projections (r2-proven 65 us version) + z=2 epilogue now also
// emits per-tile V row-sums R[bh][t][n] = sum_{s in tile t} V[s][n] (f32,
// pre-rounding, no atomics: each block fully covers its 2 tiles x 2 heads;
// quad-lane shfl reduction). z=0: Q scatter. z=1,2: transposed scatter b64.
__global__ __launch_bounds__(256, 4)
void gemm_qkv(const ushort_t* __restrict__ Xb, const ushort_t* __restrict__ Wb,
              const float* __restrict__ bq, const float* __restrict__ bk,
              const float* __restrict__ bv, ushort_t* __restrict__ Qd,
              ushort_t* __restrict__ Ktd, ushort_t* __restrict__ Vtd,
              float* __restrict__ Rs) {
  constexpr int K = 1024;
  __shared__ __align__(16) ushort_t As[128 * 64];
  __shared__ __align__(16) ushort_t Bs[128 * 64];

  const int z = blockIdx.z;
  const ushort_t* A  = Xb + (size_t)z * 8388608;
  const ushort_t* Wt = Wb + (size_t)z * 1048576;
  const float* bias = z == 0 ? bq : z == 1 ? bk : bv;
  ushort_t* Cp = z == 0 ? Qd : z == 1 ? Ktd : Vtd;

  const int tid = threadIdx.x;
  const int lane = tid & 63, w = tid >> 6;
  const int quad = lane >> 4, l16 = lane & 15;
  const int wm = w >> 1, wn = w & 1;
  const int row0 = blockIdx.x * 128;
  const int col0 = blockIdx.y * 128;

  const int sr = lane >> 3;
  const int sg = ((lane & 7) ^ (sr & 7)) * 8;
  const ushort_t* Ab = A  + (size_t)(row0 + w * 32 + sr) * K + sg;
  const ushort_t* Bb = Wt + (size_t)(col0 + w * 32 + sr) * K + sg;

  f32x4 acc[4][4] = {};

  for (int k0 = 0; k0 < K; k0 += 64) {
    __syncthreads();
#pragma unroll
    for (int i = 0; i < 4; ++i) {
      gl2lds16(Ab + (size_t)(i * 8) * K + k0, &As[(w * 32 + i * 8) * 64]);
      gl2lds16(Bb + (size_t)(i * 8) * K + k0, &Bs[(w * 32 + i * 8) * 64]);
    }
    __syncthreads();
#pragma unroll
    for (int ks = 0; ks < 2; ++ks) {
      const int kg = ((ks * 4 + quad) ^ (l16 & 7)) * 8;
      bf16x8 af[4], bfr[4];
#pragma unroll
      for (int mt = 0; mt < 4; ++mt)
        af[mt] = *(const bf16x8*)(&As[(wm * 64 + mt * 16 + l16) * 64 + kg]);
#pragma unroll
      for (int nt = 0; nt < 4; ++nt)
        bfr[nt] = *(const bf16x8*)(&Bs[(wn * 64 + nt * 16 + l16) * 64 + kg]);
#pragma unroll
      for (int mt = 0; mt < 4; ++mt)
#pragma unroll
        for (int nt = 0; nt < 4; ++nt)
          acc[mt][nt] = MFMA16(af[mt], bfr[nt], acc[mt][nt]);
    }
  }

#pragma unroll
  for (int mt = 0; mt < 4; ++mt) {
#pragma unroll
    for (int nt = 0; nt < 4; ++nt) {
      const int col = col0 + wn * 64 + nt * 16 + l16;
      const float bv4 = bias[col];
      const int rowb = row0 + wm * 64 + mt * 16 + quad * 4;
      if (z != 0) {          // transposed scatter: [b,h,hd,s], b64 over s
        const int b = rowb >> 11, s = rowb & (Sn - 1);
        const int h = col >> 6, hd = col & 63;
        us4 pk;
#pragma unroll
        for (int r = 0; r < 4; ++r) pk[r] = f2bf(acc[mt][nt][r] + bv4);
        *(us4*)(Cp + ((size_t)((b * Hn + h) * HDn + hd)) * Sn + s) = pk;
      } else {               // Q scatter: [b,h,s,hd]
#pragma unroll
        for (int r = 0; r < 4; ++r) {
          const int row = rowb + r;
          const int b = row >> 11, s = row & (Sn - 1);
          const int h = col >> 6, hd = col & 63;
          Cp[(((size_t)(b * Hn + h) * Sn + s) << 6) + hd] = f2bf(acc[mt][nt][r] + bv4);
        }
      }
    }
  }

  if (z == 2) {   // V tile row-sums: R[bh][t][n], t = wm-half (full 64 rows)
    const int b = row0 >> 11;
    const int t = ((row0 & (Sn - 1)) >> 6) + wm;
#pragma unroll
    for (int nt = 0; nt < 4; ++nt) {
      const int col = col0 + wn * 64 + nt * 16 + l16;
      const float bv4 = bias[col];
      float p = 0.f;
#pragma unroll
      for (int mt = 0; mt < 4; ++mt)
#pragma unroll
        for (int r = 0; r < 4; ++r) p += acc[mt][nt][r] + bv4;
      p += __shfl_xor(p, 16);
      p += __shfl_xor(p, 32);    // sum over quad lanes -> all 64 rows of tile
      if (quad == 0) {
        const int h = col >> 6, n = col & 63;
        Rs[((size_t)(b * Hn + h) * 32 + t) * 64 + n] = p;
      }
    }
  }
}

// Final projection: C[M,N] f32 = A[M,K]bf16 @ W[N,K]^T + bias.
__global__ __launch_bounds__(256, 4)
void gemm_out(const ushort_t* __restrict__ A, const ushort_t* __restrict__ Wt,
              const float* __restrict__ bias, float* __restrict__ Cp) {
  constexpr int K = 1024;
  __shared__ __align__(16) ushort_t As[128 * 64];
  __shared__ __align__(16) ushort_t Bs[128 * 64];

  const int tid = threadIdx.x;
  const int lane = tid & 63, w = tid >> 6;
  const int quad = lane >> 4, l16 = lane & 15;
  const int wm = w >> 1, wn = w & 1;
  const int row0 = blockIdx.x * 128;
  const int col0 = blockIdx.y * 128;

  const int sr = lane >> 3;
  const int sg = ((lane & 7) ^ (sr & 7)) * 8;
  const ushort_t* Ab = A  + (size_t)(row0 + w * 32 + sr) * K + sg;
  const ushort_t* Bb = Wt + (size_t)(col0 + w * 32 + sr) * K + sg;

  f32x4 acc[4][4] = {};

  for (int k0 = 0; k0 < K; k0 += 64) {
    __syncthreads();
#pragma unroll
    for (int i = 0; i < 4; ++i) {
      gl2lds16(Ab + (size_t)(i * 8) * K + k0, &As[(w * 32 + i * 8) * 64]);
      gl2lds16(Bb + (size_t)(i * 8) * K + k0, &Bs[(w * 32 + i * 8) * 64]);
    }
    __syncthreads();
#pragma unroll
    for (int ks = 0; ks < 2; ++ks) {
      const int kg = ((ks * 4 + quad) ^ (l16 & 7)) * 8;
      bf16x8 af[4], bfr[4];
#pragma unroll
      for (int mt = 0; mt < 4; ++mt)
        af[mt] = *(const bf16x8*)(&As[(wm * 64 + mt * 16 + l16) * 64 + kg]);
#pragma unroll
      for (int nt = 0; nt < 4; ++nt)
        bfr[nt] = *(const bf16x8*)(&Bs[(wn * 64 + nt * 16 + l16) * 64 + kg]);
#pragma unroll
      for (int mt = 0; mt < 4; ++mt)
#pragma unroll
        for (int nt = 0; nt < 4; ++nt)
          acc[mt][nt] = MFMA16(af[mt], bfr[nt], acc[mt][nt]);
    }
  }

#pragma unroll
  for (int mt = 0; mt < 4; ++mt)
#pragma unroll
    for (int nt = 0; nt < 4; ++nt) {
      const int col = col0 + wn * 64 + nt * 16 + l16;
      const float bv = bias[col];
      const int rowb = row0 + wm * 64 + mt * 16 + quad * 4;
#pragma unroll
      for (int r = 0; r < 4; ++r)
        Cp[(size_t)(rowb + r) * 1024 + col] = acc[mt][nt][r] + bv;
    }
}

// Self-prefix attention (replaces gtile + scanz + G entirely). Grid
// (x=bh 64, y=g 8): block (bh,g) owns q-tiles 4g..4g+3. Prefix Z lives only
// in the MFMA accumulator: stream K/V tiles 0..4g-1 (dbuf LDS, 8 MFMA/tile),
// then per q-tile write Z (MFMA C-layout -> swizzled Zs), advance the prefix
// with the diagonal tile's K (A-layout copy in Kp[0]) x V (already staged).
// suffV from R (computed by gemm_qkv). Same-bh blocks on one XCD: 8 bh x
// 512 KB K+V = 4 MB ~ L2, so prefix re-reads are L2-hits.
__global__ __launch_bounds__(256)
void scan_attn2(const ushort_t* __restrict__ Q, const ushort_t* __restrict__ Kt,
                const ushort_t* __restrict__ Vt, const float* __restrict__ Rs,
                ushort_t* __restrict__ O) {
  __shared__ __align__(16) ushort_t Kp[2][4096];   // prefix K dbuf; Kp[0] = diag-K A-layout in attn loop
  __shared__ __align__(16) ushort_t Vts[2][4096];  // prefix V dbuf = attn V dbuf
  __shared__ __align__(16) ushort_t Zs[4096];
  __shared__ __align__(16) ushort_t Ks[4096];
  __shared__ __align__(16) ushort_t Ss[64][72];
  __shared__ __align__(16) float sfx[4][64];

  const int tid = threadIdx.x, lane = tid & 63, w = tid >> 6;
  const int quad = lane >> 4, l16 = lane & 15;
  const int bh = blockIdx.x;           // 0..63
  const int g = blockIdx.y;            // 0..7, q-tiles 4g..4g+3
  const int qt0 = g * 4;
  const int b = bh >> 4, h = bh & 15;
  const ushort_t* Qb  = Q  + (size_t)bh * Sn * HDn;
  const ushort_t* Ktb = Kt + (size_t)bh * HDn * Sn;
  const ushort_t* Vtb = Vt + (size_t)bh * HDn * Sn;
  const float* Rb = Rs + (size_t)bh * 32 * 64;

  const int sr = lane >> 3;
  const int sg = ((lane & 7) ^ (sr & 7)) * 8;
  const int q8 = lane & 7, h8 = lane >> 3;

  // ---- prefix phase: pzacc = sum_{tau<qt0} K_tau (x) V_tau (MFMA C-layout:
  // pzacc[nt][r] = Z[d = w*16+quad*4+r][n = nt*16+l16]) ----
  f32x4 pzacc[4] = {};
  if (qt0 > 0) {
#pragma unroll
    for (int c = 0; c < 2; ++c) {
      const int row = w * 16 + c * 8;
      gl2lds16(Ktb + (size_t)(row + sr) * Sn + sg, &Kp[0][row * 64]);
      gl2lds16(Vtb + (size_t)(row + sr) * Sn + sg, &Vts[0][row * 64]);
    }
    for (int tau = 0; tau < qt0; ++tau) {
      const int pc = tau & 1;
      __syncthreads();                 // staging of buf[pc] drained
      if (tau + 1 < qt0) {             // prefetch tau+1 into other buffer
#pragma unroll
        for (int c = 0; c < 2; ++c) {
          const int row = w * 16 + c * 8;
          gl2lds16(Ktb + (size_t)(row + sr) * Sn + (tau + 1) * 64 + sg, &Kp[1 - pc][row * 64]);
          gl2lds16(Vtb + (size_t)(row + sr) * Sn + (tau + 1) * 64 + sg, &Vts[1 - pc][row * 64]);
        }
      }
#pragma unroll
      for (int ks = 0; ks < 2; ++ks) {
        const int kg = ((ks * 4 + quad) ^ (l16 & 7)) * 8;
        bf16x8 ak = *(const bf16x8*)(&Kp[pc][(w * 16 + l16) * 64 + kg]);
#pragma unroll
        for (int nt = 0; nt < 4; ++nt) {
          bf16x8 bv8 = *(const bf16x8*)(&Vts[pc][(nt * 16 + l16) * 64 + kg]);
          pzacc[nt] = MFMA16(ak, bv8, pzacc[nt]);
        }
      }
    }
    __syncthreads();                   // last prefix reads done before reuse
  }

  // ---- attn prologue: stage q-tile qt0 ----
  uint4  kvr[2][2];
  bf16x8 bqr[2][2];
  {
    const int q0 = qt0 * 64;
#pragma unroll
    for (int c = 0; c < 2; ++c) {
      const int row = w * 16 + c * 8;
      gl2lds16(Vtb + (size_t)(row + sr) * Sn + q0 + sg, &Vts[0][row * 64]);
      kvr[0][c] = *(const uint4*)(Ktb + (size_t)(w * 16 + c * 8 + h8) * Sn + q0 + q8 * 8);
    }
#pragma unroll
    for (int ks = 0; ks < 2; ++ks)
      bqr[0][ks] = *(const bf16x8*)(Qb + (size_t)(q0 + w * 16 + l16) * HDn + (ks * 4 + quad) * 8);
  }

  // local suffix-V: sfx[i][n] = sum_{tau > qt0+i} R[tau][n]
  if (tid < 64) {
    float acc = 0.f;
    for (int tau = 31; tau >= qt0; --tau) {
      if (tau < qt0 + 4) sfx[tau - qt0][tid] = acc;
      acc += Rb[(size_t)tau * 64 + tid];
    }
  }

#pragma unroll 4
  for (int i = 0; i < 4; ++i) {
    const int cur = i & 1;
    const int qt = qt0 + i, q0 = qt * 64;

    __syncthreads();   // B1: compute i-1 done (Zs/Ks/Kp0 free); i=0: sfx cover

    // write Z for this q-tile from pzacc (MFMA layout) into swizzled Zs[n][d]
#pragma unroll
    for (int nt = 0; nt < 4; ++nt) {
      const int n = nt * 16 + l16;
      const int d0 = w * 16 + quad * 4;
      us4 pk;
#pragma unroll
      for (int r = 0; r < 4; ++r) pk[r] = f2bf(SCALE * pzacc[nt][r]);
      *(us4*)(&Zs[n * 64 + (((d0 >> 3) ^ (n & 7)) << 3) + (d0 & 7)]) = pk;
    }
    // transpose-write diagonal K tile (regs -> Ks, rotated+swizzled)
#pragma unroll
    for (int c = 0; c < 2; ++c) {
      const int hd = w * 16 + c * 8 + h8;
      const int G = hd >> 3;
      const ushort_t* ku = (const ushort_t*)&kvr[cur][c];
#pragma unroll
      for (int j = 0; j < 8; ++j) {
        const int e = (j + q8) & 7;
        const int s = q8 * 8 + e;
        Ks[s * 64 + ((G ^ e) << 3) + (hd & 7)] = ku[e];
      }
    }
    // diag K ALSO in standard A-layout (for the Z advance): Kp[0]
#pragma unroll
    for (int c = 0; c < 2; ++c) {
      const int hd = w * 16 + c * 8 + h8;
      *(uint4*)(&Kp[0][hd * 64 + ((q8 ^ (hd & 7)) << 3)]) = kvr[cur][c];
    }

    __syncthreads();   // B2: ds_writes visible + V(qt) staging drained

    if (i < 3) {       // issue next-tile loads; fly under compute(i)
      const int q1 = (qt + 1) * 64, nxt = 1 - cur;
#pragma unroll
      for (int c = 0; c < 2; ++c) {
        const int row = w * 16 + c * 8;
        gl2lds16(Vtb + (size_t)(row + sr) * Sn + q1 + sg, &Vts[nxt][row * 64]);
        kvr[nxt][c] = *(const uint4*)(Ktb + (size_t)(w * 16 + c * 8 + h8) * Sn + q1 + q8 * 8);
      }
#pragma unroll
      for (int ks = 0; ks < 2; ++ks)
        bqr[nxt][ks] = *(const bf16x8*)(Qb + (size_t)(q1 + w * 16 + l16) * HDn + (ks * 4 + quad) * 8);
    }

    // ---- compute q-tile qt ----
    f32x4 oacc[4] = {};
#pragma unroll
    for (int ks = 0; ks < 2; ++ks) {        // prefix: O^T += Z' · Q^T
      const int kg = ((ks * 4 + quad) ^ (l16 & 7)) * 8;
#pragma unroll
      for (int nt = 0; nt < 4; ++nt) {
        bf16x8 az = *(const bf16x8*)(&Zs[(nt * 16 + l16) * 64 + kg]);
        oacc[nt] = MFMA16(az, bqr[cur][ks], oacc[nt]);
      }
    }
    f32x4 sacc[4] = {};
#pragma unroll
    for (int ks = 0; ks < 2; ++ks) {        // diagonal: S^T = K_d · Q^T
      const int kg = ((ks * 4 + quad) ^ (l16 & 7)) * 8;
#pragma unroll
      for (int nt = 0; nt < 4; ++nt) {
        bf16x8 ak = *(const bf16x8*)(&Ks[(nt * 16 + l16) * 64 + kg]);
        sacc[nt] = MFMA16(ak, bqr[cur][ks], sacc[nt]);
      }
    }
    const int qrel = w * 16 + l16;          // mask + scale -> Ss (b64, intra-wave)
#pragma unroll
    for (int nt = 0; nt < 4; ++nt) {
      const int kb = nt * 16 + quad * 4;
      us4 pk;
#pragma unroll
      for (int r = 0; r < 4; ++r) {
        float val = (kb + r > qrel) ? NEG : sacc[nt][r] * SCALE;
        pk[r] = f2bf(val);
      }
      *(us4*)(&Ss[qrel][kb]) = pk;
    }
#pragma unroll
    for (int ks = 0; ks < 2; ++ks) {        // O^T += V_d^T · S_d^T
      bf16x8 bs = *(const bf16x8*)(&Ss[qrel][ks * 32 + quad * 8]);
#pragma unroll
      for (int nt = 0; nt < 4; ++nt) {
        bf16x8 av = *(const bf16x8*)(&Vts[cur][(nt * 16 + l16) * 64 + (((ks * 4 + quad) ^ (l16 & 7)) << 3)]);
        oacc[nt] = MFMA16(av, bs, oacc[nt]);
      }
    }

    // masked tail + store O[b,s,d] (b64 over n)
    const int s = q0 + w * 16 + l16;
#pragma unroll
    for (int nt = 0; nt < 4; ++nt) {
      const int nb = nt * 16 + quad * 4;
      float4 s4 = *(const float4*)(&sfx[i][nb]);
      us4 pk;
      pk[0] = f2bf(oacc[nt][0] + NEG * s4.x);
      pk[1] = f2bf(oacc[nt][1] + NEG * s4.y);
      pk[2] = f2bf(oacc[nt][2] + NEG * s4.z);
      pk[3] = f2bf(oacc[nt][3] + NEG * s4.w);
      *(us4*)(&O[((size_t)(b * Sn + s)) * Dn + h * 64 + nb]) = pk;
    }

    if (i < 3) {   // advance prefix: pzacc += K_qt (x) V_qt (diag tile)
#pragma unroll
      for (int ks = 0; ks < 2; ++ks) {
        const int kg = ((ks * 4 + quad) ^ (l16 & 7)) * 8;
        bf16x8 ak = *(const bf16x8*)(&Kp[0][(w * 16 + l16) * 64 + kg]);
#pragma unroll
        for (int nt = 0; nt < 4; ++nt) {
          bf16x8 bv8 = *(const bf16x8*)(&Vts[cur][(nt * 16 + l16) * 64 + kg]);
          pzacc[nt] = MFMA16(ak, bv8, pzacc[nt]);
        }
      }
    }
  }
}

extern "C" void kernel_launch(void* const* d_in, const int* in_sizes, int n_in,
                              void* d_out, int out_size, void* d_ws, size_t ws_size,
                              hipStream_t stream) {
  const float* Xq = (const float*)d_in[0];
  const float* Xk = (const float*)d_in[1];
  const float* Xv = (const float*)d_in[2];
  // d_in[3]: causal mask (int32) — tril, handled analytically
  const float* Wq = (const float*)d_in[4];
  const float* bq = (const float*)d_in[5];
  const float* Wk = (const float*)d_in[6];
  const float* bk = (const float*)d_in[7];
  const float* Wv = (const float*)d_in[8];
  const float* bv = (const float*)d_in[9];
  const float* Wo = (const float*)d_in[10];
  const float* bo = (const float*)d_in[11];

  // ws (MiB): [0,48) Xb(3) | [48,56) Wb(4) | [56,72) Q | [72,88) Kt |
  // [88,104) Vt | [120,136) O | [176,176.5) R f32
  constexpr size_t MiB = 1024 * 1024;
  char* ws = (char*)d_ws;
  ushort_t* Xb  = (ushort_t*)(ws);
  ushort_t* Wb  = (ushort_t*)(ws + 48 * MiB);
  ushort_t* Qb  = (ushort_t*)(ws + 56 * MiB);
  ushort_t* Ktb = (ushort_t*)(ws + 72 * MiB);
  ushort_t* Vtb = (ushort_t*)(ws + 88 * MiB);
  ushort_t* Ob  = (ushort_t*)(ws + 120 * MiB);
  float*    Rsum= (float*)   (ws + 176 * MiB);

  cvt_all<<<14336, 256, 0, stream>>>(Xq, Xk, Xv, Wq, Wk, Wv, Wo, Xb, Wb);
  gemm_qkv<<<dim3(64, 8, 3), 256, 0, stream>>>(Xb, Wb, bq, bk, bv, Qb, Ktb,
                                               Vtb, Rsum);
  scan_attn2<<<dim3(64, 8), 256, 0, stream>>>(Qb, Ktb, Vtb, Rsum, Ob);
  gemm_out<<<dim3(64, 8), 256, 0, stream>>>(Ob, Wb + (size_t)3 * 1048576, bo,
                                            (float*)d_out);
}